// Round 5
// baseline (3265.292 us; speedup 1.0000x reference)
//
#include <hip/hip_runtime.h>
#include <math.h>

// Problem constants
constexpr int B  = 128;
constexpr int T  = 512;
constexpr int IN = 32;
constexpr int H  = 256;
constexpr int D  = 2 * H;     // 512
constexpr int NC = 1024;      // codebook entries

// cooperative GRU geometry
constexpr int NG   = 64;      // groups (32 fwd + 32 bwd)
constexpr int GW   = 4;       // WGs per group
constexpr int SEQ  = 4;       // sequences per group
constexpr int NTHR = 768;     // 8 k-chunks x 96 row-pairs

// dynamic-LDS pad (neutral in r4, kept: spreads 256 WGs over 256 CUs ->
// balanced 32 WGs/XCD for the claim pools)
constexpr int LDS_PAD_BYTES = 28672;

// ---------------------------------------------------------------------------
// sc0 (XCD-L2 scope) exchange primitives. sc0 = bypass L1, coherence point =
// the XCD's shared L2. Valid ONLY between CUs verified to be on the SAME XCD
// (runtime XCC_ID claim). Agent-scope fallback retained for safety.
// ---------------------------------------------------------------------------

__device__ __forceinline__ unsigned long long ld_fast(const unsigned long long* p) {
    unsigned long long v;
    asm volatile("global_load_dwordx2 %0, %1, off sc0\n\t"
                 "s_waitcnt vmcnt(0)"
                 : "=v"(v) : "v"(p) : "memory");
    return v;
}

__device__ __forceinline__ void ld_fast2(const unsigned long long* p0,
                                         const unsigned long long* p1,
                                         unsigned long long& v0,
                                         unsigned long long& v1) {
    asm volatile("global_load_dwordx2 %0, %2, off sc0\n\t"
                 "global_load_dwordx2 %1, %3, off sc0\n\t"
                 "s_waitcnt vmcnt(0)"
                 : "=&v"(v0), "=&v"(v1) : "v"(p0), "v"(p1) : "memory");
}

__device__ __forceinline__ void st_fast(unsigned long long* p, unsigned long long v) {
    asm volatile("global_store_dwordx2 %0, %1, off sc0" :: "v"(p), "v"(v) : "memory");
}

// ---------------------------------------------------------------------------
// prep kernels
// ---------------------------------------------------------------------------

// zeroes counts, lsum, the exchange slab, and the XCD claim tables.
__global__ void k_zero(int* __restrict__ counts, double* __restrict__ lsum,
                       unsigned long long* __restrict__ slab,
                       int* __restrict__ claim, int* __restrict__ slotTag) {
    const int i = blockIdx.x * 256 + threadIdx.x;
    if (i < NC) counts[i] = 0;
    if (i == 0) *lsum = 0.0;
    if (i < 8) claim[i] = 0;
    if (i < 256) slotTag[i] = 0;
    slab[i] = 0ull;
}

__global__ void k_lengths(const int* __restrict__ mask, int* __restrict__ last) {
    const int b = blockIdx.x;
    const int t = threadIdx.x;   // 64 threads = 1 wave
    int s = 0;
    #pragma unroll
    for (int m = 0; m < T / 64; ++m) s += mask[b * T + m * 64 + t];
    #pragma unroll
    for (int off = 32; off > 0; off >>= 1) s += __shfl_down(s, off, 64);
    if (t == 0) last[b] = s - 1;
}

// build direction-pure, length-sorted groups of 4 tasks
__global__ void k_plan(const int* __restrict__ last, int* __restrict__ plan,
                       int* __restrict__ slen, int* __restrict__ glen) {
    __shared__ int ll[B];
    const int t = threadIdx.x;   // 128
    ll[t] = last[t];
    __syncthreads();
    const int lf = ll[t] + 1;       // fwd steps
    const int lb = T - ll[t];       // bwd steps
    int rf = 0, rb = 0;
    for (int j = 0; j < B; ++j) {
        const int ljf = ll[j] + 1, ljb = T - ll[j];
        rf += (ljf > lf) || (ljf == lf && j < t);   // descending
        rb += (ljb > lb) || (ljb == lb && j < t);
    }
    plan[rf] = t;       slen[rf] = lf;
    plan[128 + rb] = t; slen[128 + rb] = lb;
    if ((rf & 3) == 0) glen[rf >> 2] = lf;          // rank 4g = group max
    if ((rb & 3) == 0) glen[32 + (rb >> 2)] = lb;
}

// transpose codebook for k_vq
__global__ void k_transpose(float* __restrict__ dst, const float* __restrict__ src,
                            int rows, int cols) {
    const int idx = blockIdx.x * 256 + threadIdx.x;
    const int r = idx % rows;
    const int c = idx / rows;
    dst[idx] = src[r * cols + c];
}

__global__ void k_cbn2(const float* __restrict__ cb, double* __restrict__ cbn2) {
    const int c = blockIdx.x * 256 + threadIdx.x;
    double s = 0.0;
    for (int k = 0; k < D; ++k) {
        const double e = (double)cb[c * D + k];
        s += e * e;
    }
    cbn2[c] = s;
}

// ---------------------------------------------------------------------------
// Cooperative GRU (r0 structure) + runtime XCD-verified grouping.
//
// Prologue: each WG reads HW_REG_XCC_ID, claims a slot in its XCD's 32-slot
// pool (spilling to other pools if full). Group = 4 consecutive slots, so a
// group inside one pool is co-XCD BY CONSTRUCTION. Co-XCD groups exchange
// h through their shared XCD L2 (sc0), cutting the LLC round trip; mixed
// groups keep the agent-scope path. Dual publish + periodic agent fallback
// in the loc poll makes the sc0 path deadlock-proof.
// ---------------------------------------------------------------------------

__device__ __forceinline__ float sigmoidf_(float x) {
    return 1.0f / (1.0f + expf(-x));
}

__global__ __launch_bounds__(NTHR, 3) void k_gru(
    const float* __restrict__ traj,
    const float* __restrict__ Whf, const float* __restrict__ Whb,
    const float* __restrict__ Wxf, const float* __restrict__ Wxb,
    const float* __restrict__ bxf, const float* __restrict__ bhf,
    const float* __restrict__ bxb, const float* __restrict__ bhb,
    const int* __restrict__ plan, const int* __restrict__ slen,
    const int* __restrict__ glen,
    unsigned long long* __restrict__ hgt,  // [2][NG][GW][SEQ*64] tagged pairs
    int* __restrict__ claim, int* __restrict__ slotTag,
    float* __restrict__ ze)                // [B][512]
{
    extern __shared__ float dynpad[];      // residency pad only (never touched)
    (void)dynpad;

    const int tid = threadIdx.x;

    // ---- runtime XCD claim: slot -> (g, w), loc = group fully co-XCD ----
    __shared__ int sSlot, sLoc;
    if (tid == 0) {
        int xcc;
        asm volatile("s_getreg_b32 %0, hwreg(HW_REG_XCC_ID)" : "=s"(xcc));
        xcc &= 7;
        int pool = -1, r = 0;
        for (int t2 = 0; pool < 0; ++t2) {
            const int x = (xcc + t2) & 7;
            r = atomicAdd(&claim[x], 1);
            if (r < 32) pool = x;
        }
        const int slot = pool * 32 + r;
        __hip_atomic_store(&slotTag[slot], 1 + (pool == xcc ? 1 : 0),
                           __ATOMIC_RELAXED, __HIP_MEMORY_SCOPE_AGENT);
        const int g0 = slot & ~3;
        int stat;
        do {
            stat = 2;                            // assume all claimed-home
            for (int m = 0; m < 4; ++m) {
                const int tg = __hip_atomic_load(&slotTag[g0 + m],
                                  __ATOMIC_RELAXED, __HIP_MEMORY_SCOPE_AGENT);
                if (tg == 0) { stat = 0; break; } // peer not claimed yet
                if (tg == 1) stat = (stat == 0) ? 0 : 1;  // claimed-foreign
            }
            if (stat == 0) __builtin_amdgcn_s_sleep(8);
        } while (stat == 0);
        sSlot = slot;
        sLoc  = (stat == 2);
    }
    __syncthreads();

    const int slot = sSlot;
    const int g    = slot >> 2;          // 0..63
    const int w    = slot & 3;
    const bool loc = (sLoc != 0);
    const int dir  = (g >= 32) ? 1 : 0;

    const float* __restrict__ Wh = dir ? Whb : Whf;
    const float* __restrict__ Wx = dir ? Wxb : Wxf;
    const float* __restrict__ bx = dir ? bxb : bxf;
    const float* __restrict__ bh = dir ? bhb : bhf;

    const int kq  = tid / 96;            // k-chunk 0..7 (<=2 per wave)
    const int rp  = tid - kq * 96;       // row-pair 0..95
    const int lr0 = 2 * rp;              // local gate-rows lr0, lr0+1
    const int gi  = lr0 >> 6;            // gate 0=r,1=z,2=n (same both rows)
    const int Rg0 = gi * H + w * 64 + (lr0 & 63);   // global gate-row of lr0

    __shared__ float4 h4[SEQ][64];            // full h per sequence (4 KB)
    __shared__ float  P [8][SEQ][194];        // h-dot partials [kq][s][row]
    __shared__ float  Px[8][SEQ][194];        // x-dot partials [kq][s][row]
    __shared__ float4 xb4[2][SEQ][8];         // x_t ping-pong
    __shared__ int    bbS[SEQ], lsS[SEQ];

    if (tid < SEQ) { bbS[tid] = plan[g * 4 + tid]; lsS[tid] = slen[g * 4 + tid]; }
    {   // zero h
        float2* hp = (float2*)h4;
        if (tid < 512) hp[tid] = make_float2(0.0f, 0.0f);
    }
    const int L = glen[g];

    // one-time weight load into registers: single array, round-4 shape.
    float4 wh[16];
    {
        const float4* p0 = (const float4*)(Wh + (size_t)Rg0 * 256 + kq * 32);
        const float4* p1 = (const float4*)(Wh + (size_t)(Rg0 + 1) * 256 + kq * 32);
        #pragma unroll
        for (int i = 0; i < 8; ++i) { wh[i] = p0[i]; wh[8 + i] = p1[i]; }
    }
    const float4 wx0 = *(const float4*)(Wx + Rg0 * 32 + kq * 4);
    const float4 wx1 = *(const float4*)(Wx + (Rg0 + 1) * 32 + kq * 4);

    // biases for gate threads (tid<256) in registers
    float bxr = 0, bxz = 0, bxn = 0, bhr = 0, bhz = 0, bhn = 0;
    if (tid < 256) {
        const int j2 = tid & 63;
        bxr = bx[w * 64 + j2]; bxz = bx[H + w * 64 + j2]; bxn = bx[2 * H + w * 64 + j2];
        bhr = bh[w * 64 + j2]; bhz = bh[H + w * 64 + j2]; bhn = bh[2 * H + w * 64 + j2];
    }
    __syncthreads();
    // x for step 1
    if (tid < 128) {
        const int s = tid >> 5, i = tid & 31;
        const int t0 = dir ? (T - 1) : 0;
        ((float*)xb4)[128 + s * 32 + i] = traj[(bbS[s] * T + t0) * IN + i];
    }
    __syncthreads();

    const int u = tid - 256;             // gather-thread index

    for (int step = 1; step <= L; ++step) {
        const int buf = step & 1;
        unsigned long long* __restrict__ slab =
            hgt + (buf * NG + g) * (GW * SEQ * 64);

        // ---- phase 1: partial dot products (weights in VGPRs) ----
        float4 a0 = {0,0,0,0}, a1 = {0,0,0,0}, a2 = {0,0,0,0}, a3 = {0,0,0,0};
        float4 c0 = {0,0,0,0}, c1 = {0,0,0,0}, c2 = {0,0,0,0}, c3 = {0,0,0,0};
        #pragma unroll
        for (int i = 0; i < 8; ++i) {
            const float4 w0 = wh[i];
            const float4 w1 = wh[8 + i];
            float4 hv;
            hv = h4[0][kq * 8 + i];
            a0.x = fmaf(w0.x, hv.x, a0.x); a0.y = fmaf(w0.y, hv.y, a0.y);
            a0.z = fmaf(w0.z, hv.z, a0.z); a0.w = fmaf(w0.w, hv.w, a0.w);
            c0.x = fmaf(w1.x, hv.x, c0.x); c0.y = fmaf(w1.y, hv.y, c0.y);
            c0.z = fmaf(w1.z, hv.z, c0.z); c0.w = fmaf(w1.w, hv.w, c0.w);
            hv = h4[1][kq * 8 + i];
            a1.x = fmaf(w0.x, hv.x, a1.x); a1.y = fmaf(w0.y, hv.y, a1.y);
            a1.z = fmaf(w0.z, hv.z, a1.z); a1.w = fmaf(w0.w, hv.w, a1.w);
            c1.x = fmaf(w1.x, hv.x, c1.x); c1.y = fmaf(w1.y, hv.y, c1.y);
            c1.z = fmaf(w1.z, hv.z, c1.z); c1.w = fmaf(w1.w, hv.w, c1.w);
            hv = h4[2][kq * 8 + i];
            a2.x = fmaf(w0.x, hv.x, a2.x); a2.y = fmaf(w0.y, hv.y, a2.y);
            a2.z = fmaf(w0.z, hv.z, a2.z); a2.w = fmaf(w0.w, hv.w, a2.w);
            c2.x = fmaf(w1.x, hv.x, c2.x); c2.y = fmaf(w1.y, hv.y, c2.y);
            c2.z = fmaf(w1.z, hv.z, c2.z); c2.w = fmaf(w1.w, hv.w, c2.w);
            hv = h4[3][kq * 8 + i];
            a3.x = fmaf(w0.x, hv.x, a3.x); a3.y = fmaf(w0.y, hv.y, a3.y);
            a3.z = fmaf(w0.z, hv.z, a3.z); a3.w = fmaf(w0.w, hv.w, a3.w);
            c3.x = fmaf(w1.x, hv.x, c3.x); c3.y = fmaf(w1.y, hv.y, c3.y);
            c3.z = fmaf(w1.z, hv.z, c3.z); c3.w = fmaf(w1.w, hv.w, c3.w);
        }
        // x partials (1 float4 per row per seq), uniform — no divergence
        {
            float4 xv;
            float2 pv;
            xv = xb4[buf][0][kq];
            pv.x = a0.x + a0.y + a0.z + a0.w;
            pv.y = c0.x + c0.y + c0.z + c0.w;
            *(float2*)&P[kq][0][lr0] = pv;
            pv.x = wx0.x * xv.x + wx0.y * xv.y + wx0.z * xv.z + wx0.w * xv.w;
            pv.y = wx1.x * xv.x + wx1.y * xv.y + wx1.z * xv.z + wx1.w * xv.w;
            *(float2*)&Px[kq][0][lr0] = pv;
            xv = xb4[buf][1][kq];
            pv.x = a1.x + a1.y + a1.z + a1.w;
            pv.y = c1.x + c1.y + c1.z + c1.w;
            *(float2*)&P[kq][1][lr0] = pv;
            pv.x = wx0.x * xv.x + wx0.y * xv.y + wx0.z * xv.z + wx0.w * xv.w;
            pv.y = wx1.x * xv.x + wx1.y * xv.y + wx1.z * xv.z + wx1.w * xv.w;
            *(float2*)&Px[kq][1][lr0] = pv;
            xv = xb4[buf][2][kq];
            pv.x = a2.x + a2.y + a2.z + a2.w;
            pv.y = c2.x + c2.y + c2.z + c2.w;
            *(float2*)&P[kq][2][lr0] = pv;
            pv.x = wx0.x * xv.x + wx0.y * xv.y + wx0.z * xv.z + wx0.w * xv.w;
            pv.y = wx1.x * xv.x + wx1.y * xv.y + wx1.z * xv.z + wx1.w * xv.w;
            *(float2*)&Px[kq][2][lr0] = pv;
            xv = xb4[buf][3][kq];
            pv.x = a3.x + a3.y + a3.z + a3.w;
            pv.y = c3.x + c3.y + c3.z + c3.w;
            *(float2*)&P[kq][3][lr0] = pv;
            pv.x = wx0.x * xv.x + wx0.y * xv.y + wx0.z * xv.z + wx0.w * xv.w;
            pv.y = wx1.x * xv.x + wx1.y * xv.y + wx1.z * xv.z + wx1.w * xv.w;
            *(float2*)&Px[kq][3][lr0] = pv;
        }
        __syncthreads();

        // ---- phase 2 (tid<256): gates + publish; (tid>=256): gather + x ----
        if (tid < 256) {
            const int j2 = tid & 63, s = tid >> 6;   // one s per wave
            float hr = 0.f, hz = 0.f, hn_ = 0.f, xr = 0.f, xz = 0.f, xn = 0.f;
            #pragma unroll
            for (int kk = 0; kk < 8; ++kk) {
                hr  += P [kk][s][j2];
                hz  += P [kk][s][64 + j2];
                hn_ += P [kk][s][128 + j2];
                xr  += Px[kk][s][j2];
                xz  += Px[kk][s][64 + j2];
                xn  += Px[kk][s][128 + j2];
            }
            const float r = sigmoidf_(xr + bxr + hr + bhr);
            const float z = sigmoidf_(xz + bxz + hz + bhz);
            const float n = tanhf(xn + bxn + r * (hn_ + bhn));
            const int jg = w * 64 + j2;
            const float hp = ((const float*)h4)[s * 256 + jg];
            const float hnew = (1.0f - z) * n + z * hp;
            ((float*)h4)[s * 256 + jg] = hnew;
            union { float f; unsigned ui; } cv; cv.f = hnew;
            const unsigned long long pk =
                ((unsigned long long)(unsigned)step << 32) | cv.ui;
            unsigned long long* ad = &slab[w * 256 + s * 64 + j2];
            if (loc) st_fast(ad, pk);            // XCD-L2 fast publish
            __hip_atomic_store(ad, pk,           // durable agent publish
                               __ATOMIC_RELAXED, __HIP_MEMORY_SCOPE_AGENT);
            if (step == lsS[s]) ze[bbS[s] * D + dir * H + jg] = hnew;
        } else {
            // x prefetch (issue early; completes during spins)
            float xval = 0.0f;
            int xs = 0, xi = 0;
            const bool do_x = (u < 128) && (step < L);
            if (do_x) {
                xs = u >> 5; xi = u & 31;
                const int tn = dir ? (T - 1 - step) : step;
                xval = traj[(bbS[xs] * T + tn) * IN + xi];
            }
            const int p0 = u >> 8;               // peer-list index 0,1
            const int r2 = u & 255;
            const int s0 = r2 >> 6, j0 = r2 & 63;
            const int pw0 = p0 + (p0 >= w ? 1 : 0);
            unsigned long long* ad0 = &slab[pw0 * 256 + s0 * 64 + j0];
            if (u < 256) {
                const int pw1 = 2 + (2 >= w ? 1 : 0);
                unsigned long long* ad1 = &slab[pw1 * 256 + s0 * 64 + j0];
                unsigned long long v0 = 0, v1 = 0;
                bool d0 = false, d1 = false;
                if (loc) {
                    int it = 0;
                    for (;;) {
                        unsigned long long t0, t1;
                        ld_fast2(ad0, ad1, t0, t1);
                        if (!d0 && (int)(t0 >> 32) >= step) { v0 = t0; d0 = true; }
                        if (!d1 && (int)(t1 >> 32) >= step) { v1 = t1; d1 = true; }
                        if (d0 && d1) break;
                        if ((++it & 15) == 0) {   // agent safety fallback
                            if (!d0) {
                                t0 = __hip_atomic_load(ad0, __ATOMIC_RELAXED,
                                                       __HIP_MEMORY_SCOPE_AGENT);
                                if ((int)(t0 >> 32) >= step) { v0 = t0; d0 = true; }
                            }
                            if (!d1) {
                                t1 = __hip_atomic_load(ad1, __ATOMIC_RELAXED,
                                                       __HIP_MEMORY_SCOPE_AGENT);
                                if ((int)(t1 >> 32) >= step) { v1 = t1; d1 = true; }
                            }
                            if (d0 && d1) break;
                        }
                    }
                } else {
                    do {   // concurrent double-poll: both loads in flight
                        if (!d0) { v0 = __hip_atomic_load(ad0, __ATOMIC_RELAXED,
                                       __HIP_MEMORY_SCOPE_AGENT); d0 = ((int)(v0 >> 32) >= step); }
                        if (!d1) { v1 = __hip_atomic_load(ad1, __ATOMIC_RELAXED,
                                       __HIP_MEMORY_SCOPE_AGENT); d1 = ((int)(v1 >> 32) >= step); }
                    } while (!(d0 && d1));
                }
                union { unsigned ui; float f; } e0, e1;
                e0.ui = (unsigned)v0; e1.ui = (unsigned)v1;
                ((float*)h4)[s0 * 256 + pw0 * 64 + j0] = e0.f;
                ((float*)h4)[s0 * 256 + pw1 * 64 + j0] = e1.f;
            } else {
                unsigned long long v0;
                if (loc) {
                    int it = 0;
                    for (;;) {
                        v0 = ld_fast(ad0);
                        if ((int)(v0 >> 32) >= step) break;
                        if ((++it & 15) == 0) {   // agent safety fallback
                            v0 = __hip_atomic_load(ad0, __ATOMIC_RELAXED,
                                                   __HIP_MEMORY_SCOPE_AGENT);
                            if ((int)(v0 >> 32) >= step) break;
                        }
                    }
                } else {
                    do {
                        v0 = __hip_atomic_load(ad0, __ATOMIC_RELAXED,
                                               __HIP_MEMORY_SCOPE_AGENT);
                    } while ((int)(v0 >> 32) < step);
                }
                union { unsigned ui; float f; } e0; e0.ui = (unsigned)v0;
                ((float*)h4)[s0 * 256 + pw0 * 64 + j0] = e0.f;
            }
            if (do_x)
                ((float*)xb4)[(buf ^ 1) * 128 + xs * 32 + xi] = xval;
        }
        __syncthreads();
    }
}

// ---------------------------------------------------------------------------
// VQ: fp64 distance accumulation to match the numpy (fp64) argmin ordering.
// ---------------------------------------------------------------------------

__global__ __launch_bounds__(256) void k_vq(
    const float* __restrict__ ze, const float* __restrict__ cbT,
    const float* __restrict__ cb, const double* __restrict__ cbn2,
    int* __restrict__ counts, double* __restrict__ lsum,
    float* __restrict__ out)
{
    __shared__ float lz[D];
    __shared__ double ds[256];
    __shared__ int cs[256];

    const int b = blockIdx.x;
    const int t = threadIdx.x;

    lz[t]       = ze[b * D + t];
    lz[t + 256] = ze[b * D + 256 + t];
    __syncthreads();

    double best = 1e300;
    int bc = 0;
    for (int m = 0; m < NC / 256; ++m) {
        const int c = m * 256 + t;
        double s2 = 0.0;
        #pragma unroll 4
        for (int k = 0; k < D; ++k)
            s2 += (double)lz[k] * (double)cbT[k * NC + c];
        const double dist = cbn2[c] - 2.0 * s2;
        if (dist < best) { best = dist; bc = c; }
    }
    ds[t] = best; cs[t] = bc;
    __syncthreads();
    for (int s = 128; s > 0; s >>= 1) {
        if (t < s) {
            if (ds[t + s] < ds[t] || (ds[t + s] == ds[t] && cs[t + s] < cs[t])) {
                ds[t] = ds[t + s]; cs[t] = cs[t + s];
            }
        }
        __syncthreads();
    }
    const int idx = cs[0];
    __syncthreads();

    if (t == 0) atomicAdd(&counts[idx], 1);

    double loc = 0.0;
    for (int jj = t; jj < D; jj += 256) {
        const float zev = lz[jj];
        const float zqv = cb[idx * D + jj];
        out[b * D + jj] = zev + (zqv - zev);
        const double df = (double)zqv - (double)zev;
        loc += df * df;
    }
    ds[t] = loc;
    __syncthreads();
    for (int s = 128; s > 0; s >>= 1) {
        if (t < s) ds[t] += ds[t + s];
        __syncthreads();
    }
    if (t == 0) atomicAdd(lsum, ds[0]);
}

__global__ void k_final(const int* __restrict__ counts,
                        const double* __restrict__ lsum,
                        float* __restrict__ out)
{
    __shared__ double ds[256];
    const int t = threadIdx.x;
    double s = 0.0;
    for (int c = t; c < NC; c += 256) {
        const double p = (double)counts[c] / (double)B;
        s += p * log(p + 1e-10);
    }
    ds[t] = s;
    __syncthreads();
    for (int r = 128; r > 0; r >>= 1) {
        if (t < r) ds[t] += ds[t + r];
        __syncthreads();
    }
    if (t == 0) {
        out[B * D]     = (float)(lsum[0] * 1.25 / (double)(B * D));
        out[B * D + 1] = (float)exp(-ds[0]);
    }
}

// ---------------------------------------------------------------------------
// launch
// ---------------------------------------------------------------------------

extern "C" void kernel_launch(void* const* d_in, const int* in_sizes, int n_in,
                              void* d_out, int out_size, void* d_ws, size_t ws_size,
                              hipStream_t stream) {
    const float* traj = (const float*)d_in[0];
    const int*   mask = (const int*)d_in[1];
    const float* Wxf  = (const float*)d_in[2];
    const float* Whf  = (const float*)d_in[3];
    const float* bxf  = (const float*)d_in[4];
    const float* bhf  = (const float*)d_in[5];
    const float* Wxb  = (const float*)d_in[6];
    const float* Whb  = (const float*)d_in[7];
    const float* bxb  = (const float*)d_in[8];
    const float* bhb  = (const float*)d_in[9];
    const float* cb   = (const float*)d_in[10];
    float* out = (float*)d_out;

    // workspace layout
    float* ws    = (float*)d_ws;
    float* cbT   = ws;                     // 512*1024 = 524288 floats
    float* zebuf = cbT + 524288;           // 128*512  = 65536
    unsigned long long* hgt =
        (unsigned long long*)(zebuf + 65536);   // 2*64*4*256 u64 = 131072 (1 MB)
    int*   last  = (int*)(hgt + 131072);   // 128
    int*   plan  = last + 128;             // 256
    int*   slen  = plan + 256;             // 256
    int*   glen  = slen + 256;             // 64
    int*   cnts  = glen + 64;              // 1024
    double* cbn2 = (double*)(cnts + 1024 + 4); // 1024 doubles (8B aligned)
    double* lsum = cbn2 + 1024;            // 1 double
    int*   claim = (int*)(lsum + 1);       // 8
    int*   slotT = claim + 8;              // 256

    k_zero<<<dim3(512), dim3(256), 0, stream>>>(cnts, lsum, hgt, claim, slotT);
    k_lengths<<<dim3(B), dim3(64), 0, stream>>>(mask, last);
    k_plan<<<dim3(1), dim3(B), 0, stream>>>(last, plan, slen, glen);

    k_transpose<<<dim3(2048), dim3(256), 0, stream>>>(cbT, cb, NC, D);
    k_cbn2<<<dim3(4), dim3(256), 0, stream>>>(cb, cbn2);

    k_gru<<<dim3(NG * GW), dim3(NTHR), LDS_PAD_BYTES, stream>>>(
        traj, Whf, Whb, Wxf, Wxb, bxf, bhf, bxb, bhb,
        plan, slen, glen, hgt, claim, slotT, zebuf);

    k_vq<<<dim3(B), dim3(256), 0, stream>>>(zebuf, cbT, cb, cbn2, cnts, lsum, out);
    k_final<<<dim3(1), dim3(256), 0, stream>>>(cnts, lsum, out);
}

// Round 6
// 2070.414 us; speedup vs baseline: 1.5771x; 1.5771x over previous
//
#include <hip/hip_runtime.h>
#include <math.h>

// Problem constants
constexpr int B  = 128;
constexpr int T  = 512;
constexpr int IN = 32;
constexpr int H  = 256;
constexpr int D  = 2 * H;     // 512
constexpr int NC = 1024;      // codebook entries

// cooperative GRU geometry
constexpr int NG   = 64;      // groups (32 fwd + 32 bwd)
constexpr int GW   = 4;       // WGs per group
constexpr int SEQ  = 4;       // sequences per group
constexpr int NTHR = 768;     // 8 k-chunks x 96 row-pairs

// dynamic-LDS pad (neutral in r4, kept): 55296 + 28672 > 80 KiB -> 1 WG/CU.
constexpr int LDS_PAD_BYTES = 28672;

// packed 2xfp32 FMA: d.lo += s0.lo*s1.lo ; d.hi += s0.hi*s1.hi
#define PKF(acc, w, h)                                                        \
    asm("v_pk_fma_f32 %0, %1, %2, %0" : "+v"(acc) : "v"(w), "v"(h))

// ---------------------------------------------------------------------------
// prep kernels
// ---------------------------------------------------------------------------

// zeroes counts, lsum, and the exchange slab (131072 u64 = 1 MB).
__global__ void k_zero(int* __restrict__ counts, double* __restrict__ lsum,
                       unsigned long long* __restrict__ slab) {
    const int i = blockIdx.x * 256 + threadIdx.x;
    if (i < NC) counts[i] = 0;
    if (i == 0) *lsum = 0.0;
    slab[i] = 0ull;
}

__global__ void k_lengths(const int* __restrict__ mask, int* __restrict__ last) {
    const int b = blockIdx.x;
    const int t = threadIdx.x;   // 64 threads = 1 wave
    int s = 0;
    #pragma unroll
    for (int m = 0; m < T / 64; ++m) s += mask[b * T + m * 64 + t];
    #pragma unroll
    for (int off = 32; off > 0; off >>= 1) s += __shfl_down(s, off, 64);
    if (t == 0) last[b] = s - 1;
}

// build direction-pure, length-sorted groups of 4 tasks
__global__ void k_plan(const int* __restrict__ last, int* __restrict__ plan,
                       int* __restrict__ slen, int* __restrict__ glen) {
    __shared__ int ll[B];
    const int t = threadIdx.x;   // 128
    ll[t] = last[t];
    __syncthreads();
    const int lf = ll[t] + 1;       // fwd steps
    const int lb = T - ll[t];       // bwd steps
    int rf = 0, rb = 0;
    for (int j = 0; j < B; ++j) {
        const int ljf = ll[j] + 1, ljb = T - ll[j];
        rf += (ljf > lf) || (ljf == lf && j < t);   // descending
        rb += (ljb > lb) || (ljb == lb && j < t);
    }
    plan[rf] = t;       slen[rf] = lf;
    plan[128 + rb] = t; slen[128 + rb] = lb;
    if ((rf & 3) == 0) glen[rf >> 2] = lf;          // rank 4g = group max
    if ((rb & 3) == 0) glen[32 + (rb >> 2)] = lb;
}

// transpose codebook for k_vq
__global__ void k_transpose(float* __restrict__ dst, const float* __restrict__ src,
                            int rows, int cols) {
    const int idx = blockIdx.x * 256 + threadIdx.x;
    const int r = idx % rows;
    const int c = idx / rows;
    dst[idx] = src[r * cols + c];
}

__global__ void k_cbn2(const float* __restrict__ cb, double* __restrict__ cbn2) {
    const int c = blockIdx.x * 256 + threadIdx.x;
    double s = 0.0;
    for (int k = 0; k < D; ++k) {
        const double e = (double)cb[c * D + k];
        s += e * e;
    }
    cbn2[c] = s;
}

// ---------------------------------------------------------------------------
// Cooperative GRU (r0/r4 structure; proven 1525 us).
// Round-6 deltas ONLY:
//   - phase-1 dot products use v_pk_fma_f32 (halves VALU issue on the
//     serial critical path; phase 1 does not overlap the exchange)
//   - x-prefetch moved from pollers to publisher waves, AFTER the publish
//     store (pollers keep a clean vmcnt path; x-latency hides under the
//     peers' poll window)
// Exchange protocol untouched: step-tagged u64 words, agent scope, polls
// confined to phase 2 (r2: speculative polling collapses the fabric;
// r1/r5: no working sub-LLC fast path for cross-CU spin loops).
// ---------------------------------------------------------------------------

__device__ __forceinline__ float sigmoidf_(float x) {
    return 1.0f / (1.0f + expf(-x));
}

__global__ __launch_bounds__(NTHR, 3) void k_gru(
    const float* __restrict__ traj,
    const float* __restrict__ Whf, const float* __restrict__ Whb,
    const float* __restrict__ Wxf, const float* __restrict__ Wxb,
    const float* __restrict__ bxf, const float* __restrict__ bhf,
    const float* __restrict__ bxb, const float* __restrict__ bhb,
    const int* __restrict__ plan, const int* __restrict__ slen,
    const int* __restrict__ glen,
    unsigned long long* __restrict__ hgt,  // [2][NG][GW][SEQ*64] tagged pairs
    float* __restrict__ ze)                // [B][512]
{
    extern __shared__ float dynpad[];      // residency pad only (never touched)
    (void)dynpad;

    const int g   = blockIdx.x & 63;
    const int w   = blockIdx.x >> 6;
    const int dir = (g >= 32) ? 1 : 0;

    const float* __restrict__ Wh = dir ? Whb : Whf;
    const float* __restrict__ Wx = dir ? Wxb : Wxf;
    const float* __restrict__ bx = dir ? bxb : bxf;
    const float* __restrict__ bh = dir ? bhb : bhf;

    const int tid = threadIdx.x;
    const int kq  = tid / 96;            // k-chunk 0..7 (<=2 per wave)
    const int rp  = tid - kq * 96;       // row-pair 0..95
    const int lr0 = 2 * rp;              // local gate-rows lr0, lr0+1
    const int gi  = lr0 >> 6;            // gate 0=r,1=z,2=n (same both rows)
    const int Rg0 = gi * H + w * 64 + (lr0 & 63);   // global gate-row of lr0

    __shared__ float4 h4[SEQ][64];            // full h per sequence (4 KB)
    __shared__ float  P [8][SEQ][194];        // h-dot partials [kq][s][row]
    __shared__ float  Px[8][SEQ][194];        // x-dot partials [kq][s][row]
    __shared__ float4 xb4[2][SEQ][8];         // x_t ping-pong
    __shared__ int    bbS[SEQ], lsS[SEQ];

    if (tid < SEQ) { bbS[tid] = plan[g * 4 + tid]; lsS[tid] = slen[g * 4 + tid]; }
    {   // zero h
        float2* hp = (float2*)h4;
        if (tid < 512) hp[tid] = make_float2(0.0f, 0.0f);
    }
    const int L = glen[g];

    // one-time weight load into registers, stored as float2 pairs for pk_fma.
    // whl[0..15]  = row Rg0,   k = kq*32 .. kq*32+31 (pairs)
    // whl[16..31] = row Rg0+1, same k range
    float2 whl[32];
    {
        const float4* p0 = (const float4*)(Wh + (size_t)Rg0 * 256 + kq * 32);
        const float4* p1 = (const float4*)(Wh + (size_t)(Rg0 + 1) * 256 + kq * 32);
        #pragma unroll
        for (int i = 0; i < 8; ++i) {
            const float4 t0 = p0[i];
            whl[2 * i]     = make_float2(t0.x, t0.y);
            whl[2 * i + 1] = make_float2(t0.z, t0.w);
            const float4 t1 = p1[i];
            whl[16 + 2 * i]     = make_float2(t1.x, t1.y);
            whl[16 + 2 * i + 1] = make_float2(t1.z, t1.w);
        }
    }
    float2 wx0l, wx0h, wx1l, wx1h;
    {
        const float4 x0 = *(const float4*)(Wx + Rg0 * 32 + kq * 4);
        const float4 x1 = *(const float4*)(Wx + (Rg0 + 1) * 32 + kq * 4);
        wx0l = make_float2(x0.x, x0.y); wx0h = make_float2(x0.z, x0.w);
        wx1l = make_float2(x1.x, x1.y); wx1h = make_float2(x1.z, x1.w);
    }

    // biases for gate threads (tid<256) in registers
    float bxr = 0, bxz = 0, bxn = 0, bhr = 0, bhz = 0, bhn = 0;
    if (tid < 256) {
        const int j2 = tid & 63;
        bxr = bx[w * 64 + j2]; bxz = bx[H + w * 64 + j2]; bxn = bx[2 * H + w * 64 + j2];
        bhr = bh[w * 64 + j2]; bhz = bh[H + w * 64 + j2]; bhn = bh[2 * H + w * 64 + j2];
    }
    __syncthreads();
    // x for step 1
    if (tid < 128) {
        const int s = tid >> 5, i = tid & 31;
        const int t0 = dir ? (T - 1) : 0;
        ((float*)xb4)[128 + s * 32 + i] = traj[(bbS[s] * T + t0) * IN + i];
    }
    __syncthreads();

    const int u = tid - 256;             // gather-thread index

    for (int step = 1; step <= L; ++step) {
        const int buf = step & 1;
        unsigned long long* __restrict__ slab =
            hgt + (buf * NG + g) * (GW * SEQ * 64);

        // ---- phase 1: packed partial dot products (weights in VGPRs) ----
        float2 a0l = {0,0}, a0h = {0,0}, a1l = {0,0}, a1h = {0,0};
        float2 a2l = {0,0}, a2h = {0,0}, a3l = {0,0}, a3h = {0,0};
        float2 c0l = {0,0}, c0h = {0,0}, c1l = {0,0}, c1h = {0,0};
        float2 c2l = {0,0}, c2h = {0,0}, c3l = {0,0}, c3h = {0,0};
        #pragma unroll
        for (int i = 0; i < 8; ++i) {
            const float2 w0l = whl[2 * i],      w0h = whl[2 * i + 1];
            const float2 w1l = whl[16 + 2 * i], w1h = whl[16 + 2 * i + 1];
            float4 hv; float2 hl, hh;
            hv = h4[0][kq * 8 + i];
            hl = make_float2(hv.x, hv.y); hh = make_float2(hv.z, hv.w);
            PKF(a0l, w0l, hl); PKF(a0h, w0h, hh);
            PKF(c0l, w1l, hl); PKF(c0h, w1h, hh);
            hv = h4[1][kq * 8 + i];
            hl = make_float2(hv.x, hv.y); hh = make_float2(hv.z, hv.w);
            PKF(a1l, w0l, hl); PKF(a1h, w0h, hh);
            PKF(c1l, w1l, hl); PKF(c1h, w1h, hh);
            hv = h4[2][kq * 8 + i];
            hl = make_float2(hv.x, hv.y); hh = make_float2(hv.z, hv.w);
            PKF(a2l, w0l, hl); PKF(a2h, w0h, hh);
            PKF(c2l, w1l, hl); PKF(c2h, w1h, hh);
            hv = h4[3][kq * 8 + i];
            hl = make_float2(hv.x, hv.y); hh = make_float2(hv.z, hv.w);
            PKF(a3l, w0l, hl); PKF(a3h, w0h, hh);
            PKF(c3l, w1l, hl); PKF(c3h, w1h, hh);
        }
        // x partials + horizontal sums -> P, Px (order matches original)
        {
            float4 xv; float2 xl, xh, t0, t1; float2 pv;

            xv = xb4[buf][0][kq];
            xl = make_float2(xv.x, xv.y); xh = make_float2(xv.z, xv.w);
            pv.x = (a0l.x + a0l.y) + (a0h.x + a0h.y);
            pv.y = (c0l.x + c0l.y) + (c0h.x + c0h.y);
            *(float2*)&P[kq][0][lr0] = pv;
            t0 = make_float2(0.f, 0.f); t1 = make_float2(0.f, 0.f);
            PKF(t0, wx0l, xl); PKF(t0, wx0h, xh);
            PKF(t1, wx1l, xl); PKF(t1, wx1h, xh);
            pv.x = t0.x + t0.y; pv.y = t1.x + t1.y;
            *(float2*)&Px[kq][0][lr0] = pv;

            xv = xb4[buf][1][kq];
            xl = make_float2(xv.x, xv.y); xh = make_float2(xv.z, xv.w);
            pv.x = (a1l.x + a1l.y) + (a1h.x + a1h.y);
            pv.y = (c1l.x + c1l.y) + (c1h.x + c1h.y);
            *(float2*)&P[kq][1][lr0] = pv;
            t0 = make_float2(0.f, 0.f); t1 = make_float2(0.f, 0.f);
            PKF(t0, wx0l, xl); PKF(t0, wx0h, xh);
            PKF(t1, wx1l, xl); PKF(t1, wx1h, xh);
            pv.x = t0.x + t0.y; pv.y = t1.x + t1.y;
            *(float2*)&Px[kq][1][lr0] = pv;

            xv = xb4[buf][2][kq];
            xl = make_float2(xv.x, xv.y); xh = make_float2(xv.z, xv.w);
            pv.x = (a2l.x + a2l.y) + (a2h.x + a2h.y);
            pv.y = (c2l.x + c2l.y) + (c2h.x + c2h.y);
            *(float2*)&P[kq][2][lr0] = pv;
            t0 = make_float2(0.f, 0.f); t1 = make_float2(0.f, 0.f);
            PKF(t0, wx0l, xl); PKF(t0, wx0h, xh);
            PKF(t1, wx1l, xl); PKF(t1, wx1h, xh);
            pv.x = t0.x + t0.y; pv.y = t1.x + t1.y;
            *(float2*)&Px[kq][2][lr0] = pv;

            xv = xb4[buf][3][kq];
            xl = make_float2(xv.x, xv.y); xh = make_float2(xv.z, xv.w);
            pv.x = (a3l.x + a3l.y) + (a3h.x + a3h.y);
            pv.y = (c3l.x + c3l.y) + (c3h.x + c3h.y);
            *(float2*)&P[kq][3][lr0] = pv;
            t0 = make_float2(0.f, 0.f); t1 = make_float2(0.f, 0.f);
            PKF(t0, wx0l, xl); PKF(t0, wx0h, xh);
            PKF(t1, wx1l, xl); PKF(t1, wx1h, xh);
            pv.x = t0.x + t0.y; pv.y = t1.x + t1.y;
            *(float2*)&Px[kq][3][lr0] = pv;
        }
        __syncthreads();

        // ---- phase 2 (tid<256): gates + publish + x; (tid>=256): gather ----
        if (tid < 256) {
            const int j2 = tid & 63, s = tid >> 6;   // one s per wave
            float hr = 0.f, hz = 0.f, hn_ = 0.f, xr = 0.f, xz = 0.f, xn = 0.f;
            #pragma unroll
            for (int kk = 0; kk < 8; ++kk) {
                hr  += P [kk][s][j2];
                hz  += P [kk][s][64 + j2];
                hn_ += P [kk][s][128 + j2];
                xr  += Px[kk][s][j2];
                xz  += Px[kk][s][64 + j2];
                xn  += Px[kk][s][128 + j2];
            }
            const float r = sigmoidf_(xr + bxr + hr + bhr);
            const float z = sigmoidf_(xz + bxz + hz + bhz);
            const float n = tanhf(xn + bxn + r * (hn_ + bhn));
            const int jg = w * 64 + j2;
            const float hp = ((const float*)h4)[s * 256 + jg];
            const float hnew = (1.0f - z) * n + z * hp;
            ((float*)h4)[s * 256 + jg] = hnew;
            union { float f; unsigned ui; } cv; cv.f = hnew;
            const unsigned long long pk =
                ((unsigned long long)(unsigned)step << 32) | cv.ui;
            // publish FIRST: earliest possible visibility for peer pollers
            __hip_atomic_store(&slab[w * 256 + s * 64 + j2], pk,
                               __ATOMIC_RELAXED, __HIP_MEMORY_SCOPE_AGENT);
            // x prefetch for next step (hides under the peers' poll window)
            float xval = 0.0f;
            int xs = 0, xi = 0;
            const bool do_x = (tid < 128) && (step < L);
            if (do_x) {
                xs = tid >> 5; xi = tid & 31;
                const int tn = dir ? (T - 1 - step) : step;
                xval = traj[(bbS[xs] * T + tn) * IN + xi];
            }
            if (step == lsS[s]) ze[bbS[s] * D + dir * H + jg] = hnew;
            if (do_x)
                ((float*)xb4)[(buf ^ 1) * 128 + xs * 32 + xi] = xval;
        } else {
            const int p0 = u >> 8;               // peer-list index 0,1
            const int r2 = u & 255;
            const int s0 = r2 >> 6, j0 = r2 & 63;
            const int pw0 = p0 + (p0 >= w ? 1 : 0);
            unsigned long long* ad0 = &slab[pw0 * 256 + s0 * 64 + j0];
            if (u < 256) {
                const int pw1 = 2 + (2 >= w ? 1 : 0);
                unsigned long long* ad1 = &slab[pw1 * 256 + s0 * 64 + j0];
                unsigned long long v0 = 0, v1 = 0;
                bool d0 = false, d1 = false;
                do {   // concurrent double-poll: both loads in flight
                    if (!d0) { v0 = __hip_atomic_load(ad0, __ATOMIC_RELAXED,
                                   __HIP_MEMORY_SCOPE_AGENT); d0 = ((int)(v0 >> 32) >= step); }
                    if (!d1) { v1 = __hip_atomic_load(ad1, __ATOMIC_RELAXED,
                                   __HIP_MEMORY_SCOPE_AGENT); d1 = ((int)(v1 >> 32) >= step); }
                } while (!(d0 && d1));
                union { unsigned ui; float f; } e0, e1;
                e0.ui = (unsigned)v0; e1.ui = (unsigned)v1;
                ((float*)h4)[s0 * 256 + pw0 * 64 + j0] = e0.f;
                ((float*)h4)[s0 * 256 + pw1 * 64 + j0] = e1.f;
            } else {
                unsigned long long v0;
                do {
                    v0 = __hip_atomic_load(ad0, __ATOMIC_RELAXED,
                                           __HIP_MEMORY_SCOPE_AGENT);
                } while ((int)(v0 >> 32) < step);
                union { unsigned ui; float f; } e0; e0.ui = (unsigned)v0;
                ((float*)h4)[s0 * 256 + pw0 * 64 + j0] = e0.f;
            }
        }
        __syncthreads();
    }
}

// ---------------------------------------------------------------------------
// VQ: fp64 distance accumulation to match the numpy (fp64) argmin ordering.
// ---------------------------------------------------------------------------

__global__ __launch_bounds__(256) void k_vq(
    const float* __restrict__ ze, const float* __restrict__ cbT,
    const float* __restrict__ cb, const double* __restrict__ cbn2,
    int* __restrict__ counts, double* __restrict__ lsum,
    float* __restrict__ out)
{
    __shared__ float lz[D];
    __shared__ double ds[256];
    __shared__ int cs[256];

    const int b = blockIdx.x;
    const int t = threadIdx.x;

    lz[t]       = ze[b * D + t];
    lz[t + 256] = ze[b * D + 256 + t];
    __syncthreads();

    double best = 1e300;
    int bc = 0;
    for (int m = 0; m < NC / 256; ++m) {
        const int c = m * 256 + t;
        double s2 = 0.0;
        #pragma unroll 4
        for (int k = 0; k < D; ++k)
            s2 += (double)lz[k] * (double)cbT[k * NC + c];
        const double dist = cbn2[c] - 2.0 * s2;
        if (dist < best) { best = dist; bc = c; }
    }
    ds[t] = best; cs[t] = bc;
    __syncthreads();
    for (int s = 128; s > 0; s >>= 1) {
        if (t < s) {
            if (ds[t + s] < ds[t] || (ds[t + s] == ds[t] && cs[t + s] < cs[t])) {
                ds[t] = ds[t + s]; cs[t] = cs[t + s];
            }
        }
        __syncthreads();
    }
    const int idx = cs[0];
    __syncthreads();

    if (t == 0) atomicAdd(&counts[idx], 1);

    double loc = 0.0;
    for (int jj = t; jj < D; jj += 256) {
        const float zev = lz[jj];
        const float zqv = cb[idx * D + jj];
        out[b * D + jj] = zev + (zqv - zev);
        const double df = (double)zqv - (double)zev;
        loc += df * df;
    }
    ds[t] = loc;
    __syncthreads();
    for (int s = 128; s > 0; s >>= 1) {
        if (t < s) ds[t] += ds[t + s];
        __syncthreads();
    }
    if (t == 0) atomicAdd(lsum, ds[0]);
}

__global__ void k_final(const int* __restrict__ counts,
                        const double* __restrict__ lsum,
                        float* __restrict__ out)
{
    __shared__ double ds[256];
    const int t = threadIdx.x;
    double s = 0.0;
    for (int c = t; c < NC; c += 256) {
        const double p = (double)counts[c] / (double)B;
        s += p * log(p + 1e-10);
    }
    ds[t] = s;
    __syncthreads();
    for (int r = 128; r > 0; r >>= 1) {
        if (t < r) ds[t] += ds[t + r];
        __syncthreads();
    }
    if (t == 0) {
        out[B * D]     = (float)(lsum[0] * 1.25 / (double)(B * D));
        out[B * D + 1] = (float)exp(-ds[0]);
    }
}

// ---------------------------------------------------------------------------
// launch
// ---------------------------------------------------------------------------

extern "C" void kernel_launch(void* const* d_in, const int* in_sizes, int n_in,
                              void* d_out, int out_size, void* d_ws, size_t ws_size,
                              hipStream_t stream) {
    const float* traj = (const float*)d_in[0];
    const int*   mask = (const int*)d_in[1];
    const float* Wxf  = (const float*)d_in[2];
    const float* Whf  = (const float*)d_in[3];
    const float* bxf  = (const float*)d_in[4];
    const float* bhf  = (const float*)d_in[5];
    const float* Wxb  = (const float*)d_in[6];
    const float* Whb  = (const float*)d_in[7];
    const float* bxb  = (const float*)d_in[8];
    const float* bhb  = (const float*)d_in[9];
    const float* cb   = (const float*)d_in[10];
    float* out = (float*)d_out;

    // workspace layout
    float* ws    = (float*)d_ws;
    float* cbT   = ws;                     // 512*1024 = 524288 floats
    float* zebuf = cbT + 524288;           // 128*512  = 65536
    unsigned long long* hgt =
        (unsigned long long*)(zebuf + 65536);   // 2*64*4*256 u64 = 131072 (1 MB)
    int*   last  = (int*)(hgt + 131072);   // 128
    int*   plan  = last + 128;             // 256
    int*   slen  = plan + 256;             // 256
    int*   glen  = slen + 256;             // 64
    int*   cnts  = glen + 64;              // 1024
    double* cbn2 = (double*)(cnts + 1024 + 4); // 1024 doubles (8B aligned)
    double* lsum = cbn2 + 1024;            // 1 double

    k_zero<<<dim3(512), dim3(256), 0, stream>>>(cnts, lsum, hgt);
    k_lengths<<<dim3(B), dim3(64), 0, stream>>>(mask, last);
    k_plan<<<dim3(1), dim3(B), 0, stream>>>(last, plan, slen, glen);

    k_transpose<<<dim3(2048), dim3(256), 0, stream>>>(cbT, cb, NC, D);
    k_cbn2<<<dim3(4), dim3(256), 0, stream>>>(cb, cbn2);

    k_gru<<<dim3(NG * GW), dim3(NTHR), LDS_PAD_BYTES, stream>>>(
        traj, Whf, Whb, Wxf, Wxb, bxf, bhf, bxb, bhb,
        plan, slen, glen, hgt, zebuf);

    k_vq<<<dim3(B), dim3(256), 0, stream>>>(zebuf, cbT, cb, cbn2, cnts, lsum, out);
    k_final<<<dim3(1), dim3(256), 0, stream>>>(cnts, lsum, out);
}

// Round 7
// 1727.447 us; speedup vs baseline: 1.8902x; 1.1985x over previous
//
#include <hip/hip_runtime.h>
#include <math.h>

// Problem constants
constexpr int B  = 128;
constexpr int T  = 512;
constexpr int IN = 32;
constexpr int H  = 256;
constexpr int D  = 2 * H;     // 512
constexpr int NC = 1024;      // codebook entries

// cooperative GRU geometry
constexpr int NG   = 64;      // groups (32 fwd + 32 bwd)
constexpr int GW   = 4;       // WGs per group
constexpr int SEQ  = 4;       // sequences per group
constexpr int NTHR = 768;     // 8 k-chunks x 96 row-pairs

// dynamic-LDS pad (neutral in r4, kept: 1 WG/CU residency)
constexpr int LDS_PAD_BYTES = 28672;

// ---------------------------------------------------------------------------
// prep kernels
// ---------------------------------------------------------------------------

// zeroes counts, lsum, and the exchange slab (131072 u64 = 1 MB).
__global__ void k_zero(int* __restrict__ counts, double* __restrict__ lsum,
                       unsigned long long* __restrict__ slab) {
    const int i = blockIdx.x * 256 + threadIdx.x;
    if (i < NC) counts[i] = 0;
    if (i == 0) *lsum = 0.0;
    slab[i] = 0ull;
}

__global__ void k_lengths(const int* __restrict__ mask, int* __restrict__ last) {
    const int b = blockIdx.x;
    const int t = threadIdx.x;   // 64 threads = 1 wave
    int s = 0;
    #pragma unroll
    for (int m = 0; m < T / 64; ++m) s += mask[b * T + m * 64 + t];
    #pragma unroll
    for (int off = 32; off > 0; off >>= 1) s += __shfl_down(s, off, 64);
    if (t == 0) last[b] = s - 1;
}

// build direction-pure, length-sorted groups of 4 tasks
__global__ void k_plan(const int* __restrict__ last, int* __restrict__ plan,
                       int* __restrict__ slen, int* __restrict__ glen) {
    __shared__ int ll[B];
    const int t = threadIdx.x;   // 128
    ll[t] = last[t];
    __syncthreads();
    const int lf = ll[t] + 1;       // fwd steps
    const int lb = T - ll[t];       // bwd steps
    int rf = 0, rb = 0;
    for (int j = 0; j < B; ++j) {
        const int ljf = ll[j] + 1, ljb = T - ll[j];
        rf += (ljf > lf) || (ljf == lf && j < t);   // descending
        rb += (ljb > lb) || (ljb == lb && j < t);
    }
    plan[rf] = t;       slen[rf] = lf;
    plan[128 + rb] = t; slen[128 + rb] = lb;
    if ((rf & 3) == 0) glen[rf >> 2] = lf;          // rank 4g = group max
    if ((rb & 3) == 0) glen[32 + (rb >> 2)] = lb;
}

// transpose codebook for k_vq
__global__ void k_transpose(float* __restrict__ dst, const float* __restrict__ src,
                            int rows, int cols) {
    const int idx = blockIdx.x * 256 + threadIdx.x;
    const int r = idx % rows;
    const int c = idx / rows;
    dst[idx] = src[r * cols + c];
}

__global__ void k_cbn2(const float* __restrict__ cb, double* __restrict__ cbn2) {
    const int c = blockIdx.x * 256 + threadIdx.x;
    double s = 0.0;
    for (int k = 0; k < D; ++k) {
        const double e = (double)cb[c * D + k];
        s += e * e;
    }
    cbn2[c] = s;
}

// ---------------------------------------------------------------------------
// Cooperative GRU (r0 structure, CU-exclusive residency). Best measured
// configuration: 1525 us. Per-thread: 2 rows x 32 k x 4 seqs; weights in
// VGPRs (wh[16] float4 = 64). 4 WGs/group exchange h as step-tagged 8B words
// through the LLC at agent scope, polls confined to phase 2.
// Exchange-latency engineering is closed: sc0 paths (r1/r5), speculative
// pre-gather (r2), peer-count reduction (r3), packed-FMA + prefetch
// reordering (r6) all regressed. Do not mutate the sync structure.
// ---------------------------------------------------------------------------

__device__ __forceinline__ float sigmoidf_(float x) {
    return 1.0f / (1.0f + expf(-x));
}

__global__ __launch_bounds__(NTHR, 3) void k_gru(
    const float* __restrict__ traj,
    const float* __restrict__ Whf, const float* __restrict__ Whb,
    const float* __restrict__ Wxf, const float* __restrict__ Wxb,
    const float* __restrict__ bxf, const float* __restrict__ bhf,
    const float* __restrict__ bxb, const float* __restrict__ bhb,
    const int* __restrict__ plan, const int* __restrict__ slen,
    const int* __restrict__ glen,
    unsigned long long* __restrict__ hgt,  // [2][NG][GW][SEQ*64] tagged pairs
    float* __restrict__ ze)                // [B][512]
{
    extern __shared__ float dynpad[];      // residency pad only (never touched)
    (void)dynpad;

    const int g   = blockIdx.x & 63;
    const int w   = blockIdx.x >> 6;
    const int dir = (g >= 32) ? 1 : 0;

    const float* __restrict__ Wh = dir ? Whb : Whf;
    const float* __restrict__ Wx = dir ? Wxb : Wxf;
    const float* __restrict__ bx = dir ? bxb : bxf;
    const float* __restrict__ bh = dir ? bhb : bhf;

    const int tid = threadIdx.x;
    const int kq  = tid / 96;            // k-chunk 0..7 (<=2 per wave)
    const int rp  = tid - kq * 96;       // row-pair 0..95
    const int lr0 = 2 * rp;              // local gate-rows lr0, lr0+1
    const int gi  = lr0 >> 6;            // gate 0=r,1=z,2=n (same both rows)
    const int Rg0 = gi * H + w * 64 + (lr0 & 63);   // global gate-row of lr0

    __shared__ float4 h4[SEQ][64];            // full h per sequence (4 KB)
    __shared__ float  P [8][SEQ][194];        // h-dot partials [kq][s][row]
    __shared__ float  Px[8][SEQ][194];        // x-dot partials [kq][s][row]
    __shared__ float4 xb4[2][SEQ][8];         // x_t ping-pong
    __shared__ int    bbS[SEQ], lsS[SEQ];

    if (tid < SEQ) { bbS[tid] = plan[g * 4 + tid]; lsS[tid] = slen[g * 4 + tid]; }
    {   // zero h
        float2* hp = (float2*)h4;
        if (tid < 512) hp[tid] = make_float2(0.0f, 0.0f);
    }
    const int L = glen[g];

    // one-time weight load into registers: single array, round-4 shape.
    // wh[0..7]  = row Rg0,   k = kq*32 .. kq*32+31
    // wh[8..15] = row Rg0+1, same k range
    float4 wh[16];
    {
        const float4* p0 = (const float4*)(Wh + (size_t)Rg0 * 256 + kq * 32);
        const float4* p1 = (const float4*)(Wh + (size_t)(Rg0 + 1) * 256 + kq * 32);
        #pragma unroll
        for (int i = 0; i < 8; ++i) { wh[i] = p0[i]; wh[8 + i] = p1[i]; }
    }
    const float4 wx0 = *(const float4*)(Wx + Rg0 * 32 + kq * 4);
    const float4 wx1 = *(const float4*)(Wx + (Rg0 + 1) * 32 + kq * 4);

    // biases for gate threads (tid<256) in registers
    float bxr = 0, bxz = 0, bxn = 0, bhr = 0, bhz = 0, bhn = 0;
    if (tid < 256) {
        const int j2 = tid & 63;
        bxr = bx[w * 64 + j2]; bxz = bx[H + w * 64 + j2]; bxn = bx[2 * H + w * 64 + j2];
        bhr = bh[w * 64 + j2]; bhz = bh[H + w * 64 + j2]; bhn = bh[2 * H + w * 64 + j2];
    }
    __syncthreads();
    // x for step 1
    if (tid < 128) {
        const int s = tid >> 5, i = tid & 31;
        const int t0 = dir ? (T - 1) : 0;
        ((float*)xb4)[128 + s * 32 + i] = traj[(bbS[s] * T + t0) * IN + i];
    }
    __syncthreads();

    const int u = tid - 256;             // gather-thread index

    for (int step = 1; step <= L; ++step) {
        const int buf = step & 1;
        unsigned long long* __restrict__ slab =
            hgt + (buf * NG + g) * (GW * SEQ * 64);

        // ---- phase 1: partial dot products (weights in VGPRs) ----
        float4 a0 = {0,0,0,0}, a1 = {0,0,0,0}, a2 = {0,0,0,0}, a3 = {0,0,0,0};
        float4 c0 = {0,0,0,0}, c1 = {0,0,0,0}, c2 = {0,0,0,0}, c3 = {0,0,0,0};
        #pragma unroll
        for (int i = 0; i < 8; ++i) {
            const float4 w0 = wh[i];
            const float4 w1 = wh[8 + i];
            float4 hv;
            hv = h4[0][kq * 8 + i];
            a0.x = fmaf(w0.x, hv.x, a0.x); a0.y = fmaf(w0.y, hv.y, a0.y);
            a0.z = fmaf(w0.z, hv.z, a0.z); a0.w = fmaf(w0.w, hv.w, a0.w);
            c0.x = fmaf(w1.x, hv.x, c0.x); c0.y = fmaf(w1.y, hv.y, c0.y);
            c0.z = fmaf(w1.z, hv.z, c0.z); c0.w = fmaf(w1.w, hv.w, c0.w);
            hv = h4[1][kq * 8 + i];
            a1.x = fmaf(w0.x, hv.x, a1.x); a1.y = fmaf(w0.y, hv.y, a1.y);
            a1.z = fmaf(w0.z, hv.z, a1.z); a1.w = fmaf(w0.w, hv.w, a1.w);
            c1.x = fmaf(w1.x, hv.x, c1.x); c1.y = fmaf(w1.y, hv.y, c1.y);
            c1.z = fmaf(w1.z, hv.z, c1.z); c1.w = fmaf(w1.w, hv.w, c1.w);
            hv = h4[2][kq * 8 + i];
            a2.x = fmaf(w0.x, hv.x, a2.x); a2.y = fmaf(w0.y, hv.y, a2.y);
            a2.z = fmaf(w0.z, hv.z, a2.z); a2.w = fmaf(w0.w, hv.w, a2.w);
            c2.x = fmaf(w1.x, hv.x, c2.x); c2.y = fmaf(w1.y, hv.y, c2.y);
            c2.z = fmaf(w1.z, hv.z, c2.z); c2.w = fmaf(w1.w, hv.w, c2.w);
            hv = h4[3][kq * 8 + i];
            a3.x = fmaf(w0.x, hv.x, a3.x); a3.y = fmaf(w0.y, hv.y, a3.y);
            a3.z = fmaf(w0.z, hv.z, a3.z); a3.w = fmaf(w0.w, hv.w, a3.w);
            c3.x = fmaf(w1.x, hv.x, c3.x); c3.y = fmaf(w1.y, hv.y, c3.y);
            c3.z = fmaf(w1.z, hv.z, c3.z); c3.w = fmaf(w1.w, hv.w, c3.w);
        }
        // x partials (1 float4 per row per seq), uniform — no divergence
        {
            float4 xv;
            float2 pv;
            xv = xb4[buf][0][kq];
            pv.x = a0.x + a0.y + a0.z + a0.w;
            pv.y = c0.x + c0.y + c0.z + c0.w;
            *(float2*)&P[kq][0][lr0] = pv;
            pv.x = wx0.x * xv.x + wx0.y * xv.y + wx0.z * xv.z + wx0.w * xv.w;
            pv.y = wx1.x * xv.x + wx1.y * xv.y + wx1.z * xv.z + wx1.w * xv.w;
            *(float2*)&Px[kq][0][lr0] = pv;
            xv = xb4[buf][1][kq];
            pv.x = a1.x + a1.y + a1.z + a1.w;
            pv.y = c1.x + c1.y + c1.z + c1.w;
            *(float2*)&P[kq][1][lr0] = pv;
            pv.x = wx0.x * xv.x + wx0.y * xv.y + wx0.z * xv.z + wx0.w * xv.w;
            pv.y = wx1.x * xv.x + wx1.y * xv.y + wx1.z * xv.z + wx1.w * xv.w;
            *(float2*)&Px[kq][1][lr0] = pv;
            xv = xb4[buf][2][kq];
            pv.x = a2.x + a2.y + a2.z + a2.w;
            pv.y = c2.x + c2.y + c2.z + c2.w;
            *(float2*)&P[kq][2][lr0] = pv;
            pv.x = wx0.x * xv.x + wx0.y * xv.y + wx0.z * xv.z + wx0.w * xv.w;
            pv.y = wx1.x * xv.x + wx1.y * xv.y + wx1.z * xv.z + wx1.w * xv.w;
            *(float2*)&Px[kq][2][lr0] = pv;
            xv = xb4[buf][3][kq];
            pv.x = a3.x + a3.y + a3.z + a3.w;
            pv.y = c3.x + c3.y + c3.z + c3.w;
            *(float2*)&P[kq][3][lr0] = pv;
            pv.x = wx0.x * xv.x + wx0.y * xv.y + wx0.z * xv.z + wx0.w * xv.w;
            pv.y = wx1.x * xv.x + wx1.y * xv.y + wx1.z * xv.z + wx1.w * xv.w;
            *(float2*)&Px[kq][3][lr0] = pv;
        }
        __syncthreads();

        // ---- phase 2 (tid<256): gates + publish; (tid>=256): gather + x ----
        if (tid < 256) {
            const int j2 = tid & 63, s = tid >> 6;   // one s per wave
            float hr = 0.f, hz = 0.f, hn_ = 0.f, xr = 0.f, xz = 0.f, xn = 0.f;
            #pragma unroll
            for (int kk = 0; kk < 8; ++kk) {
                hr  += P [kk][s][j2];
                hz  += P [kk][s][64 + j2];
                hn_ += P [kk][s][128 + j2];
                xr  += Px[kk][s][j2];
                xz  += Px[kk][s][64 + j2];
                xn  += Px[kk][s][128 + j2];
            }
            const float r = sigmoidf_(xr + bxr + hr + bhr);
            const float z = sigmoidf_(xz + bxz + hz + bhz);
            const float n = tanhf(xn + bxn + r * (hn_ + bhn));
            const int jg = w * 64 + j2;
            const float hp = ((const float*)h4)[s * 256 + jg];
            const float hnew = (1.0f - z) * n + z * hp;
            ((float*)h4)[s * 256 + jg] = hnew;
            union { float f; unsigned ui; } cv; cv.f = hnew;
            const unsigned long long pk =
                ((unsigned long long)(unsigned)step << 32) | cv.ui;
            __hip_atomic_store(&slab[w * 256 + s * 64 + j2], pk,
                               __ATOMIC_RELAXED, __HIP_MEMORY_SCOPE_AGENT);
            if (step == lsS[s]) ze[bbS[s] * D + dir * H + jg] = hnew;
        } else {
            // x prefetch (issue early; completes during spins)
            float xval = 0.0f;
            int xs = 0, xi = 0;
            const bool do_x = (u < 128) && (step < L);
            if (do_x) {
                xs = u >> 5; xi = u & 31;
                const int tn = dir ? (T - 1 - step) : step;
                xval = traj[(bbS[xs] * T + tn) * IN + xi];
            }
            const int p0 = u >> 8;               // peer-list index 0,1
            const int r2 = u & 255;
            const int s0 = r2 >> 6, j0 = r2 & 63;
            const int pw0 = p0 + (p0 >= w ? 1 : 0);
            unsigned long long* ad0 = &slab[pw0 * 256 + s0 * 64 + j0];
            if (u < 256) {
                const int pw1 = 2 + (2 >= w ? 1 : 0);
                unsigned long long* ad1 = &slab[pw1 * 256 + s0 * 64 + j0];
                unsigned long long v0 = 0, v1 = 0;
                bool d0 = false, d1 = false;
                do {   // concurrent double-poll: both loads in flight
                    if (!d0) { v0 = __hip_atomic_load(ad0, __ATOMIC_RELAXED,
                                   __HIP_MEMORY_SCOPE_AGENT); d0 = ((int)(v0 >> 32) >= step); }
                    if (!d1) { v1 = __hip_atomic_load(ad1, __ATOMIC_RELAXED,
                                   __HIP_MEMORY_SCOPE_AGENT); d1 = ((int)(v1 >> 32) >= step); }
                } while (!(d0 && d1));
                union { unsigned ui; float f; } e0, e1;
                e0.ui = (unsigned)v0; e1.ui = (unsigned)v1;
                ((float*)h4)[s0 * 256 + pw0 * 64 + j0] = e0.f;
                ((float*)h4)[s0 * 256 + pw1 * 64 + j0] = e1.f;
            } else {
                unsigned long long v0;
                do {
                    v0 = __hip_atomic_load(ad0, __ATOMIC_RELAXED,
                                           __HIP_MEMORY_SCOPE_AGENT);
                } while ((int)(v0 >> 32) < step);
                union { unsigned ui; float f; } e0; e0.ui = (unsigned)v0;
                ((float*)h4)[s0 * 256 + pw0 * 64 + j0] = e0.f;
            }
            if (do_x)
                ((float*)xb4)[(buf ^ 1) * 128 + xs * 32 + xi] = xval;
        }
        __syncthreads();
    }
}

// ---------------------------------------------------------------------------
// VQ: fp64 distance accumulation to match the numpy (fp64) argmin ordering.
// ---------------------------------------------------------------------------

__global__ __launch_bounds__(256) void k_vq(
    const float* __restrict__ ze, const float* __restrict__ cbT,
    const float* __restrict__ cb, const double* __restrict__ cbn2,
    int* __restrict__ counts, double* __restrict__ lsum,
    float* __restrict__ out)
{
    __shared__ float lz[D];
    __shared__ double ds[256];
    __shared__ int cs[256];

    const int b = blockIdx.x;
    const int t = threadIdx.x;

    lz[t]       = ze[b * D + t];
    lz[t + 256] = ze[b * D + 256 + t];
    __syncthreads();

    double best = 1e300;
    int bc = 0;
    for (int m = 0; m < NC / 256; ++m) {
        const int c = m * 256 + t;
        double s2 = 0.0;
        #pragma unroll 4
        for (int k = 0; k < D; ++k)
            s2 += (double)lz[k] * (double)cbT[k * NC + c];
        const double dist = cbn2[c] - 2.0 * s2;
        if (dist < best) { best = dist; bc = c; }
    }
    ds[t] = best; cs[t] = bc;
    __syncthreads();
    for (int s = 128; s > 0; s >>= 1) {
        if (t < s) {
            if (ds[t + s] < ds[t] || (ds[t + s] == ds[t] && cs[t + s] < cs[t])) {
                ds[t] = ds[t + s]; cs[t] = cs[t + s];
            }
        }
        __syncthreads();
    }
    const int idx = cs[0];
    __syncthreads();

    if (t == 0) atomicAdd(&counts[idx], 1);

    double loc = 0.0;
    for (int jj = t; jj < D; jj += 256) {
        const float zev = lz[jj];
        const float zqv = cb[idx * D + jj];
        out[b * D + jj] = zev + (zqv - zev);
        const double df = (double)zqv - (double)zev;
        loc += df * df;
    }
    ds[t] = loc;
    __syncthreads();
    for (int s = 128; s > 0; s >>= 1) {
        if (t < s) ds[t] += ds[t + s];
        __syncthreads();
    }
    if (t == 0) atomicAdd(lsum, ds[0]);
}

__global__ void k_final(const int* __restrict__ counts,
                        const double* __restrict__ lsum,
                        float* __restrict__ out)
{
    __shared__ double ds[256];
    const int t = threadIdx.x;
    double s = 0.0;
    for (int c = t; c < NC; c += 256) {
        const double p = (double)counts[c] / (double)B;
        s += p * log(p + 1e-10);
    }
    ds[t] = s;
    __syncthreads();
    for (int r = 128; r > 0; r >>= 1) {
        if (t < r) ds[t] += ds[t + r];
        __syncthreads();
    }
    if (t == 0) {
        out[B * D]     = (float)(lsum[0] * 1.25 / (double)(B * D));
        out[B * D + 1] = (float)exp(-ds[0]);
    }
}

// ---------------------------------------------------------------------------
// launch
// ---------------------------------------------------------------------------

extern "C" void kernel_launch(void* const* d_in, const int* in_sizes, int n_in,
                              void* d_out, int out_size, void* d_ws, size_t ws_size,
                              hipStream_t stream) {
    const float* traj = (const float*)d_in[0];
    const int*   mask = (const int*)d_in[1];
    const float* Wxf  = (const float*)d_in[2];
    const float* Whf  = (const float*)d_in[3];
    const float* bxf  = (const float*)d_in[4];
    const float* bhf  = (const float*)d_in[5];
    const float* Wxb  = (const float*)d_in[6];
    const float* Whb  = (const float*)d_in[7];
    const float* bxb  = (const float*)d_in[8];
    const float* bhb  = (const float*)d_in[9];
    const float* cb   = (const float*)d_in[10];
    float* out = (float*)d_out;

    // workspace layout
    float* ws    = (float*)d_ws;
    float* cbT   = ws;                     // 512*1024 = 524288 floats
    float* zebuf = cbT + 524288;           // 128*512  = 65536
    unsigned long long* hgt =
        (unsigned long long*)(zebuf + 65536);   // 2*64*4*256 u64 = 131072 (1 MB)
    int*   last  = (int*)(hgt + 131072);   // 128
    int*   plan  = last + 128;             // 256
    int*   slen  = plan + 256;             // 256
    int*   glen  = slen + 256;             // 64
    int*   cnts  = glen + 64;              // 1024
    double* cbn2 = (double*)(cnts + 1024 + 4); // 1024 doubles (8B aligned)
    double* lsum = cbn2 + 1024;            // 1 double

    k_zero<<<dim3(512), dim3(256), 0, stream>>>(cnts, lsum, hgt);
    k_lengths<<<dim3(B), dim3(64), 0, stream>>>(mask, last);
    k_plan<<<dim3(1), dim3(B), 0, stream>>>(last, plan, slen, glen);

    k_transpose<<<dim3(2048), dim3(256), 0, stream>>>(cbT, cb, NC, D);
    k_cbn2<<<dim3(4), dim3(256), 0, stream>>>(cb, cbn2);

    k_gru<<<dim3(NG * GW), dim3(NTHR), LDS_PAD_BYTES, stream>>>(
        traj, Whf, Whb, Wxf, Wxb, bxf, bhf, bxb, bhb,
        plan, slen, glen, hgt, zebuf);

    k_vq<<<dim3(B), dim3(256), 0, stream>>>(zebuf, cbT, cb, cbn2, cnts, lsum, out);
    k_final<<<dim3(1), dim3(256), 0, stream>>>(cnts, lsum, out);
}

// Round 8
// 1627.964 us; speedup vs baseline: 2.0058x; 1.0611x over previous
//
#include <hip/hip_runtime.h>
#include <math.h>

// Problem constants
constexpr int B  = 128;
constexpr int T  = 512;
constexpr int IN = 32;
constexpr int H  = 256;
constexpr int D  = 2 * H;     // 512
constexpr int NC = 1024;      // codebook entries

// cooperative GRU geometry
constexpr int NG   = 64;      // groups (32 fwd + 32 bwd)
constexpr int GW   = 4;       // WGs per group
constexpr int SEQ  = 4;       // sequences per group
constexpr int NTHR = 768;     // 8 k-chunks x 96 row-pairs

// dynamic-LDS pad (neutral in r4, kept: 1 WG/CU residency)
constexpr int LDS_PAD_BYTES = 28672;

// ---------------------------------------------------------------------------
// prep kernels
// ---------------------------------------------------------------------------

// zeroes counts, lsum, and the exchange slab (131072 u64 = 1 MB).
__global__ void k_zero(int* __restrict__ counts, double* __restrict__ lsum,
                       unsigned long long* __restrict__ slab) {
    const int i = blockIdx.x * 256 + threadIdx.x;
    if (i < NC) counts[i] = 0;
    if (i == 0) *lsum = 0.0;
    slab[i] = 0ull;
}

__global__ void k_lengths(const int* __restrict__ mask, int* __restrict__ last) {
    const int b = blockIdx.x;
    const int t = threadIdx.x;   // 64 threads = 1 wave
    int s = 0;
    #pragma unroll
    for (int m = 0; m < T / 64; ++m) s += mask[b * T + m * 64 + t];
    #pragma unroll
    for (int off = 32; off > 0; off >>= 1) s += __shfl_down(s, off, 64);
    if (t == 0) last[b] = s - 1;
}

// build direction-pure, length-sorted groups of 4 tasks
__global__ void k_plan(const int* __restrict__ last, int* __restrict__ plan,
                       int* __restrict__ slen, int* __restrict__ glen) {
    __shared__ int ll[B];
    const int t = threadIdx.x;   // 128
    ll[t] = last[t];
    __syncthreads();
    const int lf = ll[t] + 1;       // fwd steps
    const int lb = T - ll[t];       // bwd steps
    int rf = 0, rb = 0;
    for (int j = 0; j < B; ++j) {
        const int ljf = ll[j] + 1, ljb = T - ll[j];
        rf += (ljf > lf) || (ljf == lf && j < t);   // descending
        rb += (ljb > lb) || (ljb == lb && j < t);
    }
    plan[rf] = t;       slen[rf] = lf;
    plan[128 + rb] = t; slen[128 + rb] = lb;
    if ((rf & 3) == 0) glen[rf >> 2] = lf;          // rank 4g = group max
    if ((rb & 3) == 0) glen[32 + (rb >> 2)] = lb;
}

// transpose codebook for k_vq
__global__ void k_transpose(float* __restrict__ dst, const float* __restrict__ src,
                            int rows, int cols) {
    const int idx = blockIdx.x * 256 + threadIdx.x;
    const int r = idx % rows;
    const int c = idx / rows;
    dst[idx] = src[r * cols + c];
}

__global__ void k_cbn2(const float* __restrict__ cb, double* __restrict__ cbn2) {
    const int c = blockIdx.x * 256 + threadIdx.x;
    double s = 0.0;
    for (int k = 0; k < D; ++k) {
        const double e = (double)cb[c * D + k];
        s += e * e;
    }
    cbn2[c] = s;
}

// ---------------------------------------------------------------------------
// Cooperative GRU (r0 structure, CU-exclusive residency).
// r8 delta (single variable): phase-2 gather redistributed so ALL 768
// threads poll exactly ONE word (publishers poll peer-list index 0 after
// their store; gather threads poll peers 1-2). Previously 256 threads
// polled 2 words each (serialized max-of-2 straggle) while publishers
// idled. Everything else — slab layout, tags, agent scope, barriers,
// race chain, x-prefetch placement — is byte-identical to the 1480 us r7.
// Exchange-protocol engineering remains closed (r1/r2/r3/r5/r6 all
// regressed); this is a work-distribution change inside the proven protocol.
// ---------------------------------------------------------------------------

__device__ __forceinline__ float sigmoidf_(float x) {
    return 1.0f / (1.0f + expf(-x));
}

__global__ __launch_bounds__(NTHR, 3) void k_gru(
    const float* __restrict__ traj,
    const float* __restrict__ Whf, const float* __restrict__ Whb,
    const float* __restrict__ Wxf, const float* __restrict__ Wxb,
    const float* __restrict__ bxf, const float* __restrict__ bhf,
    const float* __restrict__ bxb, const float* __restrict__ bhb,
    const int* __restrict__ plan, const int* __restrict__ slen,
    const int* __restrict__ glen,
    unsigned long long* __restrict__ hgt,  // [2][NG][GW][SEQ*64] tagged pairs
    float* __restrict__ ze)                // [B][512]
{
    extern __shared__ float dynpad[];      // residency pad only (never touched)
    (void)dynpad;

    const int g   = blockIdx.x & 63;
    const int w   = blockIdx.x >> 6;
    const int dir = (g >= 32) ? 1 : 0;

    const float* __restrict__ Wh = dir ? Whb : Whf;
    const float* __restrict__ Wx = dir ? Wxb : Wxf;
    const float* __restrict__ bx = dir ? bxb : bxf;
    const float* __restrict__ bh = dir ? bhb : bhf;

    const int tid = threadIdx.x;
    const int kq  = tid / 96;            // k-chunk 0..7 (<=2 per wave)
    const int rp  = tid - kq * 96;       // row-pair 0..95
    const int lr0 = 2 * rp;              // local gate-rows lr0, lr0+1
    const int gi  = lr0 >> 6;            // gate 0=r,1=z,2=n (same both rows)
    const int Rg0 = gi * H + w * 64 + (lr0 & 63);   // global gate-row of lr0

    __shared__ float4 h4[SEQ][64];            // full h per sequence (4 KB)
    __shared__ float  P [8][SEQ][194];        // h-dot partials [kq][s][row]
    __shared__ float  Px[8][SEQ][194];        // x-dot partials [kq][s][row]
    __shared__ float4 xb4[2][SEQ][8];         // x_t ping-pong
    __shared__ int    bbS[SEQ], lsS[SEQ];

    if (tid < SEQ) { bbS[tid] = plan[g * 4 + tid]; lsS[tid] = slen[g * 4 + tid]; }
    {   // zero h
        float2* hp = (float2*)h4;
        if (tid < 512) hp[tid] = make_float2(0.0f, 0.0f);
    }
    const int L = glen[g];

    // one-time weight load into registers: single array, round-4 shape.
    // wh[0..7]  = row Rg0,   k = kq*32 .. kq*32+31
    // wh[8..15] = row Rg0+1, same k range
    float4 wh[16];
    {
        const float4* p0 = (const float4*)(Wh + (size_t)Rg0 * 256 + kq * 32);
        const float4* p1 = (const float4*)(Wh + (size_t)(Rg0 + 1) * 256 + kq * 32);
        #pragma unroll
        for (int i = 0; i < 8; ++i) { wh[i] = p0[i]; wh[8 + i] = p1[i]; }
    }
    const float4 wx0 = *(const float4*)(Wx + Rg0 * 32 + kq * 4);
    const float4 wx1 = *(const float4*)(Wx + (Rg0 + 1) * 32 + kq * 4);

    // biases for gate threads (tid<256) in registers
    float bxr = 0, bxz = 0, bxn = 0, bhr = 0, bhz = 0, bhn = 0;
    if (tid < 256) {
        const int j2 = tid & 63;
        bxr = bx[w * 64 + j2]; bxz = bx[H + w * 64 + j2]; bxn = bx[2 * H + w * 64 + j2];
        bhr = bh[w * 64 + j2]; bhz = bh[H + w * 64 + j2]; bhn = bh[2 * H + w * 64 + j2];
    }
    __syncthreads();
    // x for step 1
    if (tid < 128) {
        const int s = tid >> 5, i = tid & 31;
        const int t0 = dir ? (T - 1) : 0;
        ((float*)xb4)[128 + s * 32 + i] = traj[(bbS[s] * T + t0) * IN + i];
    }
    __syncthreads();

    const int u = tid - 256;             // gather-thread index

    for (int step = 1; step <= L; ++step) {
        const int buf = step & 1;
        unsigned long long* __restrict__ slab =
            hgt + (buf * NG + g) * (GW * SEQ * 64);

        // ---- phase 1: partial dot products (weights in VGPRs) ----
        float4 a0 = {0,0,0,0}, a1 = {0,0,0,0}, a2 = {0,0,0,0}, a3 = {0,0,0,0};
        float4 c0 = {0,0,0,0}, c1 = {0,0,0,0}, c2 = {0,0,0,0}, c3 = {0,0,0,0};
        #pragma unroll
        for (int i = 0; i < 8; ++i) {
            const float4 w0 = wh[i];
            const float4 w1 = wh[8 + i];
            float4 hv;
            hv = h4[0][kq * 8 + i];
            a0.x = fmaf(w0.x, hv.x, a0.x); a0.y = fmaf(w0.y, hv.y, a0.y);
            a0.z = fmaf(w0.z, hv.z, a0.z); a0.w = fmaf(w0.w, hv.w, a0.w);
            c0.x = fmaf(w1.x, hv.x, c0.x); c0.y = fmaf(w1.y, hv.y, c0.y);
            c0.z = fmaf(w1.z, hv.z, c0.z); c0.w = fmaf(w1.w, hv.w, c0.w);
            hv = h4[1][kq * 8 + i];
            a1.x = fmaf(w0.x, hv.x, a1.x); a1.y = fmaf(w0.y, hv.y, a1.y);
            a1.z = fmaf(w0.z, hv.z, a1.z); a1.w = fmaf(w0.w, hv.w, a1.w);
            c1.x = fmaf(w1.x, hv.x, c1.x); c1.y = fmaf(w1.y, hv.y, c1.y);
            c1.z = fmaf(w1.z, hv.z, c1.z); c1.w = fmaf(w1.w, hv.w, c1.w);
            hv = h4[2][kq * 8 + i];
            a2.x = fmaf(w0.x, hv.x, a2.x); a2.y = fmaf(w0.y, hv.y, a2.y);
            a2.z = fmaf(w0.z, hv.z, a2.z); a2.w = fmaf(w0.w, hv.w, a2.w);
            c2.x = fmaf(w1.x, hv.x, c2.x); c2.y = fmaf(w1.y, hv.y, c2.y);
            c2.z = fmaf(w1.z, hv.z, c2.z); c2.w = fmaf(w1.w, hv.w, c2.w);
            hv = h4[3][kq * 8 + i];
            a3.x = fmaf(w0.x, hv.x, a3.x); a3.y = fmaf(w0.y, hv.y, a3.y);
            a3.z = fmaf(w0.z, hv.z, a3.z); a3.w = fmaf(w0.w, hv.w, a3.w);
            c3.x = fmaf(w1.x, hv.x, c3.x); c3.y = fmaf(w1.y, hv.y, c3.y);
            c3.z = fmaf(w1.z, hv.z, c3.z); c3.w = fmaf(w1.w, hv.w, c3.w);
        }
        // x partials (1 float4 per row per seq), uniform — no divergence
        {
            float4 xv;
            float2 pv;
            xv = xb4[buf][0][kq];
            pv.x = a0.x + a0.y + a0.z + a0.w;
            pv.y = c0.x + c0.y + c0.z + c0.w;
            *(float2*)&P[kq][0][lr0] = pv;
            pv.x = wx0.x * xv.x + wx0.y * xv.y + wx0.z * xv.z + wx0.w * xv.w;
            pv.y = wx1.x * xv.x + wx1.y * xv.y + wx1.z * xv.z + wx1.w * xv.w;
            *(float2*)&Px[kq][0][lr0] = pv;
            xv = xb4[buf][1][kq];
            pv.x = a1.x + a1.y + a1.z + a1.w;
            pv.y = c1.x + c1.y + c1.z + c1.w;
            *(float2*)&P[kq][1][lr0] = pv;
            pv.x = wx0.x * xv.x + wx0.y * xv.y + wx0.z * xv.z + wx0.w * xv.w;
            pv.y = wx1.x * xv.x + wx1.y * xv.y + wx1.z * xv.z + wx1.w * xv.w;
            *(float2*)&Px[kq][1][lr0] = pv;
            xv = xb4[buf][2][kq];
            pv.x = a2.x + a2.y + a2.z + a2.w;
            pv.y = c2.x + c2.y + c2.z + c2.w;
            *(float2*)&P[kq][2][lr0] = pv;
            pv.x = wx0.x * xv.x + wx0.y * xv.y + wx0.z * xv.z + wx0.w * xv.w;
            pv.y = wx1.x * xv.x + wx1.y * xv.y + wx1.z * xv.z + wx1.w * xv.w;
            *(float2*)&Px[kq][2][lr0] = pv;
            xv = xb4[buf][3][kq];
            pv.x = a3.x + a3.y + a3.z + a3.w;
            pv.y = c3.x + c3.y + c3.z + c3.w;
            *(float2*)&P[kq][3][lr0] = pv;
            pv.x = wx0.x * xv.x + wx0.y * xv.y + wx0.z * xv.z + wx0.w * xv.w;
            pv.y = wx1.x * xv.x + wx1.y * xv.y + wx1.z * xv.z + wx1.w * xv.w;
            *(float2*)&Px[kq][3][lr0] = pv;
        }
        __syncthreads();

        // ---- phase 2: gates+publish (tid<256) then EVERY thread polls ONE
        //      word. 768 words / 768 threads: publishers take peer-list
        //      index 0, gather threads take indices 1-2. ----
        if (tid < 256) {
            const int j2 = tid & 63, s = tid >> 6;   // one s per wave
            float hr = 0.f, hz = 0.f, hn_ = 0.f, xr = 0.f, xz = 0.f, xn = 0.f;
            #pragma unroll
            for (int kk = 0; kk < 8; ++kk) {
                hr  += P [kk][s][j2];
                hz  += P [kk][s][64 + j2];
                hn_ += P [kk][s][128 + j2];
                xr  += Px[kk][s][j2];
                xz  += Px[kk][s][64 + j2];
                xn  += Px[kk][s][128 + j2];
            }
            const float r = sigmoidf_(xr + bxr + hr + bhr);
            const float z = sigmoidf_(xz + bxz + hz + bhz);
            const float n = tanhf(xn + bxn + r * (hn_ + bhn));
            const int jg = w * 64 + j2;
            const float hp = ((const float*)h4)[s * 256 + jg];
            const float hnew = (1.0f - z) * n + z * hp;
            ((float*)h4)[s * 256 + jg] = hnew;
            union { float f; unsigned ui; } cv; cv.f = hnew;
            const unsigned long long pk =
                ((unsigned long long)(unsigned)step << 32) | cv.ui;
            __hip_atomic_store(&slab[w * 256 + s * 64 + j2], pk,
                               __ATOMIC_RELAXED, __HIP_MEMORY_SCOPE_AGENT);
            if (step == lsS[s]) ze[bbS[s] * D + dir * H + jg] = hnew;
            // poll ONE word: peer-list index 0, same (s, j2) slot as ours.
            // The waitcnt also drains our publish store (~1 RT) — earlier
            // than typical peer visibility, so not on the critical path.
            const int pw0 = (0 >= w) ? 1 : 0;
            unsigned long long* ad0 = &slab[pw0 * 256 + s * 64 + j2];
            unsigned long long v0;
            do {
                v0 = __hip_atomic_load(ad0, __ATOMIC_RELAXED,
                                       __HIP_MEMORY_SCOPE_AGENT);
            } while ((int)(v0 >> 32) < step);
            union { unsigned ui; float f; } e0; e0.ui = (unsigned)v0;
            ((float*)h4)[s * 256 + pw0 * 64 + j2] = e0.f;
        } else {
            // x prefetch (issue early; completes during spins)
            float xval = 0.0f;
            int xs = 0, xi = 0;
            const bool do_x = (u < 128) && (step < L);
            if (do_x) {
                xs = u >> 5; xi = u & 31;
                const int tn = dir ? (T - 1 - step) : step;
                xval = traj[(bbS[xs] * T + tn) * IN + xi];
            }
            const int pi = 1 + (u >> 8);         // peer-list index 1,2
            const int r2 = u & 255;
            const int s0 = r2 >> 6, j0 = r2 & 63;
            const int pw0 = pi + (pi >= w ? 1 : 0);
            unsigned long long* ad0 = &slab[pw0 * 256 + s0 * 64 + j0];
            unsigned long long v0;
            do {
                v0 = __hip_atomic_load(ad0, __ATOMIC_RELAXED,
                                       __HIP_MEMORY_SCOPE_AGENT);
            } while ((int)(v0 >> 32) < step);
            union { unsigned ui; float f; } e0; e0.ui = (unsigned)v0;
            ((float*)h4)[s0 * 256 + pw0 * 64 + j0] = e0.f;
            if (do_x)
                ((float*)xb4)[(buf ^ 1) * 128 + xs * 32 + xi] = xval;
        }
        __syncthreads();
    }
}

// ---------------------------------------------------------------------------
// VQ: fp64 distance accumulation to match the numpy (fp64) argmin ordering.
// ---------------------------------------------------------------------------

__global__ __launch_bounds__(256) void k_vq(
    const float* __restrict__ ze, const float* __restrict__ cbT,
    const float* __restrict__ cb, const double* __restrict__ cbn2,
    int* __restrict__ counts, double* __restrict__ lsum,
    float* __restrict__ out)
{
    __shared__ float lz[D];
    __shared__ double ds[256];
    __shared__ int cs[256];

    const int b = blockIdx.x;
    const int t = threadIdx.x;

    lz[t]       = ze[b * D + t];
    lz[t + 256] = ze[b * D + 256 + t];
    __syncthreads();

    double best = 1e300;
    int bc = 0;
    for (int m = 0; m < NC / 256; ++m) {
        const int c = m * 256 + t;
        double s2 = 0.0;
        #pragma unroll 4
        for (int k = 0; k < D; ++k)
            s2 += (double)lz[k] * (double)cbT[k * NC + c];
        const double dist = cbn2[c] - 2.0 * s2;
        if (dist < best) { best = dist; bc = c; }
    }
    ds[t] = best; cs[t] = bc;
    __syncthreads();
    for (int s = 128; s > 0; s >>= 1) {
        if (t < s) {
            if (ds[t + s] < ds[t] || (ds[t + s] == ds[t] && cs[t + s] < cs[t])) {
                ds[t] = ds[t + s]; cs[t] = cs[t + s];
            }
        }
        __syncthreads();
    }
    const int idx = cs[0];
    __syncthreads();

    if (t == 0) atomicAdd(&counts[idx], 1);

    double loc = 0.0;
    for (int jj = t; jj < D; jj += 256) {
        const float zev = lz[jj];
        const float zqv = cb[idx * D + jj];
        out[b * D + jj] = zev + (zqv - zev);
        const double df = (double)zqv - (double)zev;
        loc += df * df;
    }
    ds[t] = loc;
    __syncthreads();
    for (int s = 128; s > 0; s >>= 1) {
        if (t < s) ds[t] += ds[t + s];
        __syncthreads();
    }
    if (t == 0) atomicAdd(lsum, ds[0]);
}

__global__ void k_final(const int* __restrict__ counts,
                        const double* __restrict__ lsum,
                        float* __restrict__ out)
{
    __shared__ double ds[256];
    const int t = threadIdx.x;
    double s = 0.0;
    for (int c = t; c < NC; c += 256) {
        const double p = (double)counts[c] / (double)B;
        s += p * log(p + 1e-10);
    }
    ds[t] = s;
    __syncthreads();
    for (int r = 128; r > 0; r >>= 1) {
        if (t < r) ds[t] += ds[t + r];
        __syncthreads();
    }
    if (t == 0) {
        out[B * D]     = (float)(lsum[0] * 1.25 / (double)(B * D));
        out[B * D + 1] = (float)exp(-ds[0]);
    }
}

// ---------------------------------------------------------------------------
// launch
// ---------------------------------------------------------------------------

extern "C" void kernel_launch(void* const* d_in, const int* in_sizes, int n_in,
                              void* d_out, int out_size, void* d_ws, size_t ws_size,
                              hipStream_t stream) {
    const float* traj = (const float*)d_in[0];
    const int*   mask = (const int*)d_in[1];
    const float* Wxf  = (const float*)d_in[2];
    const float* Whf  = (const float*)d_in[3];
    const float* bxf  = (const float*)d_in[4];
    const float* bhf  = (const float*)d_in[5];
    const float* Wxb  = (const float*)d_in[6];
    const float* Whb  = (const float*)d_in[7];
    const float* bxb  = (const float*)d_in[8];
    const float* bhb  = (const float*)d_in[9];
    const float* cb   = (const float*)d_in[10];
    float* out = (float*)d_out;

    // workspace layout
    float* ws    = (float*)d_ws;
    float* cbT   = ws;                     // 512*1024 = 524288 floats
    float* zebuf = cbT + 524288;           // 128*512  = 65536
    unsigned long long* hgt =
        (unsigned long long*)(zebuf + 65536);   // 2*64*4*256 u64 = 131072 (1 MB)
    int*   last  = (int*)(hgt + 131072);   // 128
    int*   plan  = last + 128;             // 256
    int*   slen  = plan + 256;             // 256
    int*   glen  = slen + 256;             // 64
    int*   cnts  = glen + 64;              // 1024
    double* cbn2 = (double*)(cnts + 1024 + 4); // 1024 doubles (8B aligned)
    double* lsum = cbn2 + 1024;            // 1 double

    k_zero<<<dim3(512), dim3(256), 0, stream>>>(cnts, lsum, hgt);
    k_lengths<<<dim3(B), dim3(64), 0, stream>>>(mask, last);
    k_plan<<<dim3(1), dim3(B), 0, stream>>>(last, plan, slen, glen);

    k_transpose<<<dim3(2048), dim3(256), 0, stream>>>(cbT, cb, NC, D);
    k_cbn2<<<dim3(4), dim3(256), 0, stream>>>(cb, cbn2);

    k_gru<<<dim3(NG * GW), dim3(NTHR), LDS_PAD_BYTES, stream>>>(
        traj, Whf, Whb, Wxf, Wxb, bxf, bhf, bxb, bhb,
        plan, slen, glen, hgt, zebuf);

    k_vq<<<dim3(B), dim3(256), 0, stream>>>(zebuf, cbT, cb, cbn2, cnts, lsum, out);
    k_final<<<dim3(1), dim3(256), 0, stream>>>(cnts, lsum, out);
}